// Round 8
// baseline (385.335 us; speedup 1.0000x reference)
//
#include <hip/hip_runtime.h>
#include <hip/hip_bf16.h>

// GCN GraphConv (norm='both', mult-first): out = relu( D_in^-1/2 * A * D_out^-1/2 * (X W) + b )
// N=100000 nodes, E=3200000 edges, IN=128, OUT=64, fp32 in/out.
//
// Strategy R8:
//  - partition: LDS counting-sort + coalesced flush (R7), with deg_out
//    histogram atomics issued in the FINAL loop (no trailing barrier -> no
//    vmcnt drain until kernel end; 24 waves/CU of latency cover).
//  - gemm: clean scaled version (deg_out ready after partition), register-
//    blocked 4 rows/thread so each W LDS read feeds 4 FMAs.
//  - csr counting sort + vectorized gather unchanged.

constexpr int N_NODES = 100000;
constexpr int N_EDGES = 3200000;
constexpr int IN_F    = 128;
constexpr int OUT_F   = 64;
constexpr int BUCKET_NODES = 256;
constexpr int NB   = (N_NODES + BUCKET_NODES - 1) / BUCKET_NODES;  // 391
constexpr int CAPB = 10240;          // bucket capacity; mean 8184, sd~90 -> 22 sigma
constexpr int C_CHUNK  = 4096;
constexpr int C_BLOCKS = (N_EDGES + C_CHUNK - 1) / C_CHUNK;        // 782
constexpr int R_TILE   = 16;         // gemm rows per block-iteration

// ---- Kernel 1: partition + deg_out histogram ----
__global__ __launch_bounds__(512) void partition_kernel(
        const int* __restrict__ src, const int* __restrict__ dst,
        int* __restrict__ deg_out_i, int* __restrict__ bucket_cnt,
        unsigned* __restrict__ pairs) {
    __shared__ int l_cnt[NB];
    __shared__ int l_base[NB];
    __shared__ int l_pos[NB];
    __shared__ int g_base[NB];
    __shared__ int wsum_s[8];
    __shared__ unsigned buf[C_CHUNK];            // 16 KB
    __shared__ unsigned short bkt_of[C_CHUNK];   // 8 KB
    const int tid  = threadIdx.x;
    const int lane = tid & 63;
    const int wid  = tid >> 6;                   // 0..7
    const long e0 = (long)blockIdx.x * C_CHUNK;
    const int  cn = (int)min((long)C_CHUNK, (long)N_EDGES - e0);

    for (int i = tid; i < NB; i += 512) l_cnt[i] = 0;
    __syncthreads();

    // load edges into registers, count buckets
    unsigned r_pk[8];
    short    r_bk[8];
    #pragma unroll
    for (int k = 0; k < 8; ++k) {
        int i = tid + k * 512;
        r_bk[k] = -1;
        if (i < cn) {
            int d = dst[e0 + i];
            int s = src[e0 + i];
            int bk = d >> 8;
            r_bk[k] = (short)bk;
            r_pk[k] = ((unsigned)(d & 255) << 17) | (unsigned)s;
            atomicAdd(&l_cnt[bk], 1);
        }
    }
    __syncthreads();

    // exclusive scan of l_cnt[0..NB) over 512 threads; reserve global runs
    {
        int v = (tid < NB) ? l_cnt[tid] : 0;
        int inc = v;
        #pragma unroll
        for (int off = 1; off < 64; off <<= 1) {
            int t = __shfl_up(inc, off);
            if (lane >= off) inc += t;
        }
        if (lane == 63) wsum_s[wid] = inc;
        __syncthreads();
        int woff = 0;
        #pragma unroll
        for (int w = 0; w < 8; ++w) if (w < wid) woff += wsum_s[w];
        int excl = woff + inc - v;
        if (tid < NB) {
            l_base[tid] = excl;
            l_pos[tid]  = excl;
            g_base[tid] = v ? atomicAdd(&bucket_cnt[tid], v) : 0;
        }
    }
    __syncthreads();

    // scatter into LDS (counting sort by bucket)
    #pragma unroll
    for (int k = 0; k < 8; ++k) {
        if (r_bk[k] >= 0) {
            int p = atomicAdd(&l_pos[(int)r_bk[k]], 1);
            buf[p] = r_pk[k];
            bkt_of[p] = (unsigned short)r_bk[k];
        }
    }
    __syncthreads();

    // FINAL loop (no trailing barrier): coalesced pairs flush + fire-and-forget
    // deg_out atomics. vmcnt only drains at kernel end.
    for (int i = tid; i < cn; i += 512) {
        unsigned e = buf[i];
        int bk = bkt_of[i];
        int gp = g_base[bk] + (i - l_base[bk]);
        if (gp < CAPB)                            // 22-sigma safety, never taken
            pairs[(long)bk * CAPB + gp] = e;
        atomicAdd(&deg_out_i[e & 0x1FFFF], 1);
    }
}

// ---- Kernel 2: sxw[n,:] = bf16( (X[n,:] @ W) * rsqrt(max(deg_out[n],1)) ) ----
// 16 rows per block-iteration; each thread handles 4 rows x 1 col, so each
// W LDS read feeds 4 FMAs (W LDS traffic /4 vs row-per-wave version).
__global__ __launch_bounds__(256) void gemm_scale_kernel(
        const float* __restrict__ x, const float* __restrict__ W,
        const int* __restrict__ deg_out_i, __hip_bfloat16* __restrict__ sxw) {
    __shared__ float Wl[IN_F * OUT_F];    // 32 KB
    __shared__ float xl[R_TILE * IN_F];   // 8 KB
    const int tid = threadIdx.x;
    for (int i = tid; i < IN_F * OUT_F; i += 256) Wl[i] = W[i];

    const int sub = tid >> 6;             // wave 0..3 -> rows sub*4 .. sub*4+3
    const int col = tid & 63;
    const int n_groups = N_NODES / R_TILE;   // 6250, exact

    for (int g = blockIdx.x; g < n_groups; g += gridDim.x) {
        __syncthreads();
        const float4* xg = (const float4*)(x + (long)g * R_TILE * IN_F);
        float4* xl4 = (float4*)xl;
        xl4[tid]       = xg[tid];
        xl4[tid + 256] = xg[tid + 256];
        __syncthreads();

        float a0 = 0.0f, a1 = 0.0f, a2 = 0.0f, a3 = 0.0f;
        const float* xr = &xl[sub * 4 * IN_F];
        #pragma unroll
        for (int k4 = 0; k4 < IN_F / 4; ++k4) {
            float4 x0 = ((const float4*)xr)[k4];
            float4 x1 = ((const float4*)(xr + IN_F))[k4];
            float4 x2 = ((const float4*)(xr + 2 * IN_F))[k4];
            float4 x3 = ((const float4*)(xr + 3 * IN_F))[k4];
            float w0 = Wl[(k4 * 4 + 0) * OUT_F + col];
            float w1 = Wl[(k4 * 4 + 1) * OUT_F + col];
            float w2 = Wl[(k4 * 4 + 2) * OUT_F + col];
            float w3 = Wl[(k4 * 4 + 3) * OUT_F + col];
            a0 += x0.x * w0 + x0.y * w1 + x0.z * w2 + x0.w * w3;
            a1 += x1.x * w0 + x1.y * w1 + x1.z * w2 + x1.w * w3;
            a2 += x2.x * w0 + x2.y * w1 + x2.z * w2 + x2.w * w3;
            a3 += x3.x * w0 + x3.y * w1 + x3.z * w2 + x3.w * w3;
        }

        const int r0 = g * R_TILE + sub * 4;
        int d0 = deg_out_i[r0 + 0], d1 = deg_out_i[r0 + 1];
        int d2 = deg_out_i[r0 + 2], d3 = deg_out_i[r0 + 3];
        float s0 = rsqrtf((float)(d0 < 1 ? 1 : d0));
        float s1 = rsqrtf((float)(d1 < 1 ? 1 : d1));
        float s2 = rsqrtf((float)(d2 < 1 ? 1 : d2));
        float s3 = rsqrtf((float)(d3 < 1 ? 1 : d3));
        sxw[(long)(r0 + 0) * OUT_F + col] = __float2bfloat16(a0 * s0);
        sxw[(long)(r0 + 1) * OUT_F + col] = __float2bfloat16(a1 * s1);
        sxw[(long)(r0 + 2) * OUT_F + col] = __float2bfloat16(a2 * s2);
        sxw[(long)(r0 + 3) * OUT_F + col] = __float2bfloat16(a3 * s3);
    }
}

// ---- Kernel 3: per-bucket LDS counting sort -> row_beg/row_deg + sorted src ----
__global__ __launch_bounds__(512) void csr_kernel(
        unsigned* __restrict__ pairs, const int* __restrict__ bucket_cnt,
        int* __restrict__ row_beg, int* __restrict__ row_deg) {
    __shared__ int hist[BUCKET_NODES];
    __shared__ int cur[BUCKET_NODES];
    __shared__ int wsum[4];
    __shared__ unsigned buf[CAPB];       // 40 KB
    const int tid  = threadIdx.x;
    const int lane = tid & 63;
    const int wid  = tid >> 6;
    const int bk   = blockIdx.x;
    const long base = (long)bk * CAPB;
    const int cnt  = min(bucket_cnt[bk], CAPB);

    if (tid < 256) hist[tid] = 0;
    __syncthreads();

    for (int i = tid; i < cnt; i += 512) {
        unsigned e = pairs[base + i];
        buf[i] = e;
        atomicAdd(&hist[e >> 17], 1);
    }
    __syncthreads();

    int v = (tid < 256) ? hist[tid] : 0;
    int inc = v;
    #pragma unroll
    for (int off = 1; off < 64; off <<= 1) {
        int t = __shfl_up(inc, off);
        if (lane >= off) inc += t;
    }
    if (tid < 256 && lane == 63) wsum[wid] = inc;
    __syncthreads();
    if (tid < 256) {
        int woff = 0;
        #pragma unroll
        for (int w = 0; w < 4; ++w) if (w < wid) woff += wsum[w];
        int excl = woff + inc - v;
        cur[tid] = excl;
        const int node = bk * BUCKET_NODES + tid;
        if (node < N_NODES) {
            row_beg[node] = (int)(base + excl);
            row_deg[node] = v;
        }
    }
    __syncthreads();

    for (int i = tid; i < cnt; i += 512) {
        unsigned e = buf[i];
        int p = atomicAdd(&cur[e >> 17], 1);
        pairs[base + p] = e & 0x1FFFF;   // plain src, node-sorted
    }
}

// ---- Kernel 4: gather-sum per dst node, 8B loads, fused norm+bias+relu ----
__global__ __launch_bounds__(256) void gather_kernel(
        const int* __restrict__ row_beg, const int* __restrict__ row_deg,
        const unsigned* __restrict__ csr_src, const uint2* __restrict__ sxw2,
        const float* __restrict__ b, float* __restrict__ out) {
    const int lane = threadIdx.x & 63;
    const int node = blockIdx.x * 4 + (threadIdx.x >> 6);
    if (node >= N_NODES) return;

    const int eo = lane >> 4;     // edge slot 0..3
    const int c  = lane & 15;     // uint2 index within row (4 cols)

    const int beg = row_beg[node];
    const int deg = row_deg[node];
    const int end = beg + deg;

    float a0 = 0.0f, a1 = 0.0f, a2 = 0.0f, a3 = 0.0f;

    int j = beg;
    for (; j + 8 <= end; j += 8) {
        unsigned sA = csr_src[j + eo];
        unsigned sB = csr_src[j + 4 + eo];
        uint2 uA = sxw2[(long)sA * 16 + c];
        uint2 uB = sxw2[(long)sB * 16 + c];
        a0 += __uint_as_float(uA.x << 16);
        a1 += __uint_as_float(uA.x & 0xFFFF0000u);
        a2 += __uint_as_float(uA.y << 16);
        a3 += __uint_as_float(uA.y & 0xFFFF0000u);
        a0 += __uint_as_float(uB.x << 16);
        a1 += __uint_as_float(uB.x & 0xFFFF0000u);
        a2 += __uint_as_float(uB.y << 16);
        a3 += __uint_as_float(uB.y & 0xFFFF0000u);
    }
    for (; j < end; j += 4) {
        int e = j + eo;
        if (e < end) {
            unsigned s = csr_src[e];
            uint2 u = sxw2[(long)s * 16 + c];
            a0 += __uint_as_float(u.x << 16);
            a1 += __uint_as_float(u.x & 0xFFFF0000u);
            a2 += __uint_as_float(u.y << 16);
            a3 += __uint_as_float(u.y & 0xFFFF0000u);
        }
    }

    a0 += __shfl_xor(a0, 16); a0 += __shfl_xor(a0, 32);
    a1 += __shfl_xor(a1, 16); a1 += __shfl_xor(a1, 32);
    a2 += __shfl_xor(a2, 16); a2 += __shfl_xor(a2, 32);
    a3 += __shfl_xor(a3, 16); a3 += __shfl_xor(a3, 32);

    if (lane < 16) {
        float d = (float)(deg < 1 ? 1 : deg);
        float s = rsqrtf(d);
        float4 bb = ((const float4*)b)[c];
        float4 o;
        o.x = a0 * s + bb.x; o.x = o.x > 0.0f ? o.x : 0.0f;
        o.y = a1 * s + bb.y; o.y = o.y > 0.0f ? o.y : 0.0f;
        o.z = a2 * s + bb.z; o.z = o.z > 0.0f ? o.z : 0.0f;
        o.w = a3 * s + bb.w; o.w = o.w > 0.0f ? o.w : 0.0f;
        ((float4*)(out + (long)node * OUT_F))[c] = o;
    }
}

extern "C" void kernel_launch(void* const* d_in, const int* in_sizes, int n_in,
                              void* d_out, int out_size, void* d_ws, size_t ws_size,
                              hipStream_t stream) {
    const float* in_feat = (const float*)d_in[0];
    const int*   src     = (const int*)d_in[1];
    const int*   dst     = (const int*)d_in[2];
    const float* W       = (const float*)d_in[3];
    const float* b       = (const float*)d_in[4];
    float*       out     = (float*)d_out;

    // ws: sxw bf16 [N*64] (12.8MB) | deg_out [N] | bucket_cnt [NB] | row_beg [N]
    //   | row_deg [N] | pairs [NB*CAPB u32] (16MB)   total ~30 MB
    __hip_bfloat16* sxw        = (__hip_bfloat16*)d_ws;
    int*            deg_out_i  = (int*)(sxw + (size_t)N_NODES * OUT_F);
    int*            bucket_cnt = deg_out_i + N_NODES;
    int*            row_beg    = bucket_cnt + NB;
    int*            row_deg    = row_beg + N_NODES;
    unsigned*       pairs      = (unsigned*)(row_deg + N_NODES);

    hipMemsetAsync(deg_out_i, 0, (size_t)(N_NODES + NB) * sizeof(int), stream);

    partition_kernel<<<C_BLOCKS, 512, 0, stream>>>(src, dst, deg_out_i,
                                                   bucket_cnt, pairs);

    gemm_scale_kernel<<<2048, 256, 0, stream>>>(in_feat, W, deg_out_i, sxw);

    csr_kernel<<<NB, 512, 0, stream>>>(pairs, bucket_cnt, row_beg, row_deg);

    gather_kernel<<<(N_NODES + 3) / 4, 256, 0, stream>>>(row_beg, row_deg, pairs,
                                                         (const uint2*)sxw, b, out);
}

// Round 9
// 371.755 us; speedup vs baseline: 1.0365x; 1.0365x over previous
//
#include <hip/hip_runtime.h>
#include <hip/hip_bf16.h>

// GCN GraphConv (norm='both', mult-first): out = relu( D_in^-1/2 * A * D_out^-1/2 * (X W) + b )
// N=100000 nodes, E=3200000 edges, IN=128, OUT=64, fp32 in/out.
//
// Strategy R9:
//  - deg_out: standalone max-TLP kernel with 4-way COPY STRIPING (copies in
//    distinct cache lines -> same-line RMW serialization /4). gemm sums copies.
//  - partition: clean LDS counting-sort + coalesced flush (no atomics in tail).
//  - gather: uint4 (16B) loads, 8 lanes/edge, 2x unrolled -> VMEM instrs /2.
//  - csr counting sort unchanged.

constexpr int N_NODES = 100000;
constexpr int N_EDGES = 3200000;
constexpr int IN_F    = 128;
constexpr int OUT_F   = 64;
constexpr int BUCKET_NODES = 256;
constexpr int NB   = (N_NODES + BUCKET_NODES - 1) / BUCKET_NODES;  // 391
constexpr int CAPB = 10240;          // bucket capacity; mean 8184, sd~90 -> 22 sigma
constexpr int C_CHUNK  = 4096;
constexpr int C_BLOCKS = (N_EDGES + C_CHUNK - 1) / C_CHUNK;        // 782
constexpr int R_TILE   = 16;         // gemm rows per block-iteration

// ---- Kernel 1: deg_out histogram, 4-way striped copies ----
__global__ __launch_bounds__(256) void deg_kernel(
        const int* __restrict__ src, int* __restrict__ deg4) {
    int e = blockIdx.x * 256 + threadIdx.x;
    if (e < N_EDGES)
        atomicAdd(&deg4[(blockIdx.x & 3) * N_NODES + src[e]], 1);
}

// ---- Kernel 2: partition edges into fixed-capacity buckets (clean) ----
__global__ __launch_bounds__(512) void partition_kernel(
        const int* __restrict__ src, const int* __restrict__ dst,
        int* __restrict__ bucket_cnt, unsigned* __restrict__ pairs) {
    __shared__ int l_cnt[NB];
    __shared__ int l_base[NB];
    __shared__ int l_pos[NB];
    __shared__ int g_base[NB];
    __shared__ int wsum_s[8];
    __shared__ unsigned buf[C_CHUNK];            // 16 KB
    __shared__ unsigned short bkt_of[C_CHUNK];   // 8 KB
    const int tid  = threadIdx.x;
    const int lane = tid & 63;
    const int wid  = tid >> 6;                   // 0..7
    const long e0 = (long)blockIdx.x * C_CHUNK;
    const int  cn = (int)min((long)C_CHUNK, (long)N_EDGES - e0);

    for (int i = tid; i < NB; i += 512) l_cnt[i] = 0;
    __syncthreads();

    unsigned r_pk[8];
    short    r_bk[8];
    #pragma unroll
    for (int k = 0; k < 8; ++k) {
        int i = tid + k * 512;
        r_bk[k] = -1;
        if (i < cn) {
            int d = dst[e0 + i];
            int s = src[e0 + i];
            int bk = d >> 8;
            r_bk[k] = (short)bk;
            r_pk[k] = ((unsigned)(d & 255) << 17) | (unsigned)s;
            atomicAdd(&l_cnt[bk], 1);
        }
    }
    __syncthreads();

    {   // exclusive scan of l_cnt[0..NB); reserve global runs
        int v = (tid < NB) ? l_cnt[tid] : 0;
        int inc = v;
        #pragma unroll
        for (int off = 1; off < 64; off <<= 1) {
            int t = __shfl_up(inc, off);
            if (lane >= off) inc += t;
        }
        if (lane == 63) wsum_s[wid] = inc;
        __syncthreads();
        int woff = 0;
        #pragma unroll
        for (int w = 0; w < 8; ++w) if (w < wid) woff += wsum_s[w];
        int excl = woff + inc - v;
        if (tid < NB) {
            l_base[tid] = excl;
            l_pos[tid]  = excl;
            g_base[tid] = v ? atomicAdd(&bucket_cnt[tid], v) : 0;
        }
    }
    __syncthreads();

    #pragma unroll
    for (int k = 0; k < 8; ++k) {
        if (r_bk[k] >= 0) {
            int p = atomicAdd(&l_pos[(int)r_bk[k]], 1);
            buf[p] = r_pk[k];
            bkt_of[p] = (unsigned short)r_bk[k];
        }
    }
    __syncthreads();

    // coalesced flush: consecutive i -> consecutive global slot within run
    for (int i = tid; i < cn; i += 512) {
        int bk = bkt_of[i];
        int gp = g_base[bk] + (i - l_base[bk]);
        if (gp < CAPB)                            // 22-sigma safety, never taken
            pairs[(long)bk * CAPB + gp] = buf[i];
    }
}

// ---- Kernel 3: sxw[n,:] = bf16( (X[n,:] @ W) * rsqrt(max(deg_out[n],1)) ) ----
// deg_out[n] = sum of 4 striped copies.
__global__ __launch_bounds__(256) void gemm_scale_kernel(
        const float* __restrict__ x, const float* __restrict__ W,
        const int* __restrict__ deg4, __hip_bfloat16* __restrict__ sxw) {
    __shared__ float Wl[IN_F * OUT_F];    // 32 KB
    __shared__ float xl[R_TILE * IN_F];   // 8 KB
    const int tid = threadIdx.x;
    for (int i = tid; i < IN_F * OUT_F; i += 256) Wl[i] = W[i];

    const int sub = tid >> 6;             // wave 0..3 -> rows sub*4 .. sub*4+3
    const int col = tid & 63;
    const int n_groups = N_NODES / R_TILE;   // 6250, exact

    for (int g = blockIdx.x; g < n_groups; g += gridDim.x) {
        __syncthreads();
        const float4* xg = (const float4*)(x + (long)g * R_TILE * IN_F);
        float4* xl4 = (float4*)xl;
        xl4[tid]       = xg[tid];
        xl4[tid + 256] = xg[tid + 256];
        __syncthreads();

        float a0 = 0.0f, a1 = 0.0f, a2 = 0.0f, a3 = 0.0f;
        const float* xr = &xl[sub * 4 * IN_F];
        #pragma unroll
        for (int k4 = 0; k4 < IN_F / 4; ++k4) {
            float4 x0 = ((const float4*)xr)[k4];
            float4 x1 = ((const float4*)(xr + IN_F))[k4];
            float4 x2 = ((const float4*)(xr + 2 * IN_F))[k4];
            float4 x3 = ((const float4*)(xr + 3 * IN_F))[k4];
            float w0 = Wl[(k4 * 4 + 0) * OUT_F + col];
            float w1 = Wl[(k4 * 4 + 1) * OUT_F + col];
            float w2 = Wl[(k4 * 4 + 2) * OUT_F + col];
            float w3 = Wl[(k4 * 4 + 3) * OUT_F + col];
            a0 += x0.x * w0 + x0.y * w1 + x0.z * w2 + x0.w * w3;
            a1 += x1.x * w0 + x1.y * w1 + x1.z * w2 + x1.w * w3;
            a2 += x2.x * w0 + x2.y * w1 + x2.z * w2 + x2.w * w3;
            a3 += x3.x * w0 + x3.y * w1 + x3.z * w2 + x3.w * w3;
        }

        const int r0 = g * R_TILE + sub * 4;
        int d0 = 0, d1 = 0, d2 = 0, d3 = 0;
        #pragma unroll
        for (int k = 0; k < 4; ++k) {
            const int* dk = deg4 + k * N_NODES + r0;
            d0 += dk[0]; d1 += dk[1]; d2 += dk[2]; d3 += dk[3];
        }
        float s0 = rsqrtf((float)(d0 < 1 ? 1 : d0));
        float s1 = rsqrtf((float)(d1 < 1 ? 1 : d1));
        float s2 = rsqrtf((float)(d2 < 1 ? 1 : d2));
        float s3 = rsqrtf((float)(d3 < 1 ? 1 : d3));
        sxw[(long)(r0 + 0) * OUT_F + col] = __float2bfloat16(a0 * s0);
        sxw[(long)(r0 + 1) * OUT_F + col] = __float2bfloat16(a1 * s1);
        sxw[(long)(r0 + 2) * OUT_F + col] = __float2bfloat16(a2 * s2);
        sxw[(long)(r0 + 3) * OUT_F + col] = __float2bfloat16(a3 * s3);
    }
}

// ---- Kernel 4: per-bucket LDS counting sort -> row_beg/row_deg + sorted src ----
__global__ __launch_bounds__(512) void csr_kernel(
        unsigned* __restrict__ pairs, const int* __restrict__ bucket_cnt,
        int* __restrict__ row_beg, int* __restrict__ row_deg) {
    __shared__ int hist[BUCKET_NODES];
    __shared__ int cur[BUCKET_NODES];
    __shared__ int wsum[4];
    __shared__ unsigned buf[CAPB];       // 40 KB
    const int tid  = threadIdx.x;
    const int lane = tid & 63;
    const int wid  = tid >> 6;
    const int bk   = blockIdx.x;
    const long base = (long)bk * CAPB;
    const int cnt  = min(bucket_cnt[bk], CAPB);

    if (tid < 256) hist[tid] = 0;
    __syncthreads();

    for (int i = tid; i < cnt; i += 512) {
        unsigned e = pairs[base + i];
        buf[i] = e;
        atomicAdd(&hist[e >> 17], 1);
    }
    __syncthreads();

    int v = (tid < 256) ? hist[tid] : 0;
    int inc = v;
    #pragma unroll
    for (int off = 1; off < 64; off <<= 1) {
        int t = __shfl_up(inc, off);
        if (lane >= off) inc += t;
    }
    if (tid < 256 && lane == 63) wsum[wid] = inc;
    __syncthreads();
    if (tid < 256) {
        int woff = 0;
        #pragma unroll
        for (int w = 0; w < 4; ++w) if (w < wid) woff += wsum[w];
        int excl = woff + inc - v;
        cur[tid] = excl;
        const int node = bk * BUCKET_NODES + tid;
        if (node < N_NODES) {
            row_beg[node] = (int)(base + excl);
            row_deg[node] = v;
        }
    }
    __syncthreads();

    for (int i = tid; i < cnt; i += 512) {
        unsigned e = buf[i];
        int p = atomicAdd(&cur[e >> 17], 1);
        pairs[base + p] = e & 0x1FFFF;   // plain src, node-sorted
    }
}

// ---- Kernel 5: gather-sum per dst node, uint4 (16B) loads ----
// 8 lanes/edge (uint4 = 8 bf16 cols), 8 edge slots/wave, 2x unrolled.
#define ACC8(u)                                   \
    a0 += __uint_as_float((u).x << 16);           \
    a1 += __uint_as_float((u).x & 0xFFFF0000u);   \
    a2 += __uint_as_float((u).y << 16);           \
    a3 += __uint_as_float((u).y & 0xFFFF0000u);   \
    a4 += __uint_as_float((u).z << 16);           \
    a5 += __uint_as_float((u).z & 0xFFFF0000u);   \
    a6 += __uint_as_float((u).w << 16);           \
    a7 += __uint_as_float((u).w & 0xFFFF0000u);

__global__ __launch_bounds__(256) void gather_kernel(
        const int* __restrict__ row_beg, const int* __restrict__ row_deg,
        const unsigned* __restrict__ csr_src, const uint4* __restrict__ sxw4,
        const float* __restrict__ b, float* __restrict__ out) {
    const int lane = threadIdx.x & 63;
    const int node = blockIdx.x * 4 + (threadIdx.x >> 6);
    if (node >= N_NODES) return;

    const int eo = lane >> 3;     // edge slot 0..7
    const int c  = lane & 7;      // uint4 index within row (8 cols)

    const int beg = row_beg[node];
    const int deg = row_deg[node];
    const int end = beg + deg;

    float a0 = 0, a1 = 0, a2 = 0, a3 = 0, a4 = 0, a5 = 0, a6 = 0, a7 = 0;

    int j = beg;
    for (; j + 16 <= end; j += 16) {            // 2 loads in flight
        unsigned sA = csr_src[j + eo];
        unsigned sB = csr_src[j + 8 + eo];
        uint4 uA = sxw4[(long)sA * 8 + c];
        uint4 uB = sxw4[(long)sB * 8 + c];
        ACC8(uA)
        ACC8(uB)
    }
    for (; j + 8 <= end; j += 8) {
        unsigned s = csr_src[j + eo];
        uint4 u = sxw4[(long)s * 8 + c];
        ACC8(u)
    }
    if (j < end) {                               // predicated tail (<8 edges)
        int e = j + eo;
        if (e < end) {
            unsigned s = csr_src[e];
            uint4 u = sxw4[(long)s * 8 + c];
            ACC8(u)
        }
    }

    // fold the 8 edge slots (xor over eo bits: 8, 16, 32)
    #pragma unroll
    for (int off = 8; off < 64; off <<= 1) {
        a0 += __shfl_xor(a0, off);
        a1 += __shfl_xor(a1, off);
        a2 += __shfl_xor(a2, off);
        a3 += __shfl_xor(a3, off);
        a4 += __shfl_xor(a4, off);
        a5 += __shfl_xor(a5, off);
        a6 += __shfl_xor(a6, off);
        a7 += __shfl_xor(a7, off);
    }

    if (lane < 8) {                              // lane == c; cols c*8 .. c*8+7
        float d = (float)(deg < 1 ? 1 : deg);
        float s = rsqrtf(d);
        float4 b0 = ((const float4*)b)[c * 2];
        float4 b1 = ((const float4*)b)[c * 2 + 1];
        float4 o0, o1;
        o0.x = a0 * s + b0.x; o0.x = o0.x > 0.0f ? o0.x : 0.0f;
        o0.y = a1 * s + b0.y; o0.y = o0.y > 0.0f ? o0.y : 0.0f;
        o0.z = a2 * s + b0.z; o0.z = o0.z > 0.0f ? o0.z : 0.0f;
        o0.w = a3 * s + b0.w; o0.w = o0.w > 0.0f ? o0.w : 0.0f;
        o1.x = a4 * s + b1.x; o1.x = o1.x > 0.0f ? o1.x : 0.0f;
        o1.y = a5 * s + b1.y; o1.y = o1.y > 0.0f ? o1.y : 0.0f;
        o1.z = a6 * s + b1.z; o1.z = o1.z > 0.0f ? o1.z : 0.0f;
        o1.w = a7 * s + b1.w; o1.w = o1.w > 0.0f ? o1.w : 0.0f;
        float4* orow = (float4*)(out + (long)node * OUT_F);
        orow[c * 2]     = o0;
        orow[c * 2 + 1] = o1;
    }
}

extern "C" void kernel_launch(void* const* d_in, const int* in_sizes, int n_in,
                              void* d_out, int out_size, void* d_ws, size_t ws_size,
                              hipStream_t stream) {
    const float* in_feat = (const float*)d_in[0];
    const int*   src     = (const int*)d_in[1];
    const int*   dst     = (const int*)d_in[2];
    const float* W       = (const float*)d_in[3];
    const float* b       = (const float*)d_in[4];
    float*       out     = (float*)d_out;

    // ws: sxw bf16 [N*64] (12.8MB) | deg4 [4N] (1.6MB) | bucket_cnt [NB]
    //   | row_beg [N] | row_deg [N] | pairs [NB*CAPB u32] (16MB)  ~31.5 MB
    __hip_bfloat16* sxw        = (__hip_bfloat16*)d_ws;
    int*            deg4       = (int*)(sxw + (size_t)N_NODES * OUT_F);
    int*            bucket_cnt = deg4 + 4 * N_NODES;
    int*            row_beg    = bucket_cnt + NB;
    int*            row_deg    = row_beg + N_NODES;
    unsigned*       pairs      = (unsigned*)(row_deg + N_NODES);

    hipMemsetAsync(deg4, 0, (size_t)(4 * N_NODES + NB) * sizeof(int), stream);

    deg_kernel<<<(N_EDGES + 255) / 256, 256, 0, stream>>>(src, deg4);

    partition_kernel<<<C_BLOCKS, 512, 0, stream>>>(src, dst, bucket_cnt, pairs);

    gemm_scale_kernel<<<2048, 256, 0, stream>>>(in_feat, W, deg4, sxw);

    csr_kernel<<<NB, 512, 0, stream>>>(pairs, bucket_cnt, row_beg, row_deg);

    gather_kernel<<<(N_NODES + 3) / 4, 256, 0, stream>>>(row_beg, row_deg, pairs,
                                                         (const uint4*)sxw, b, out);
}

// Round 10
// 269.242 us; speedup vs baseline: 1.4312x; 1.3807x over previous
//
#include <hip/hip_runtime.h>
#include <hip/hip_bf16.h>

// GCN GraphConv (norm='both', mult-first): out = relu( D_in^-1/2 * A * D_out^-1/2 * (X W) + b )
// N=100000 nodes, E=3200000 edges, IN=128, OUT=64, fp32 in/out.
//
// Strategy R10: NO global atomics anywhere.
//  - partition: dual LDS counting sort in one pass — dst-keyed 4B pairs (for
//    CSR) AND src-keyed 1B local-id stream (for deg_out), both flushed as
//    coalesced runs. src bucket/local-id come free from the packed pair bits.
//  - count: per-src-bucket LDS histogram of the byte stream -> deg_out.
//  - gemm (register-blocked), csr counting sort, uint4 gather unchanged.

constexpr int N_NODES = 100000;
constexpr int N_EDGES = 3200000;
constexpr int IN_F    = 128;
constexpr int OUT_F   = 64;
constexpr int BUCKET_NODES = 256;
constexpr int NB   = (N_NODES + BUCKET_NODES - 1) / BUCKET_NODES;  // 391
constexpr int CAPB = 10240;          // bucket capacity; mean 8184, sd~90 -> 22 sigma
constexpr int C_CHUNK  = 4096;
constexpr int C_BLOCKS = (N_EDGES + C_CHUNK - 1) / C_CHUNK;        // 782
constexpr int R_TILE   = 16;         // gemm rows per block-iteration

// ---- Kernel 1: dual partition (dst pairs + src bytes), no global atomics
//      beyond one run-reservation per (block,bucket) ----
__global__ __launch_bounds__(512) void partition_kernel(
        const int* __restrict__ src, const int* __restrict__ dst,
        int* __restrict__ bucket_cnt, int* __restrict__ bucket_cnt2,
        unsigned* __restrict__ pairs, unsigned char* __restrict__ sbytes) {
    __shared__ int l_cnt [NB], l_base [NB], l_pos [NB], g_base [NB];
    __shared__ int l_cnt2[NB], l_base2[NB], l_pos2[NB], g_base2[NB];
    __shared__ int wsum_s[8];
    __shared__ unsigned buf[C_CHUNK];             // 16 KB (dst-sorted pairs)
    __shared__ unsigned short bkt_of[C_CHUNK];    // 8 KB
    __shared__ unsigned char  bbuf[C_CHUNK];      // 4 KB (src-sorted local ids)
    __shared__ unsigned short bkt2_of[C_CHUNK];   // 8 KB
    const int tid  = threadIdx.x;
    const int lane = tid & 63;
    const int wid  = tid >> 6;                    // 0..7
    const long e0 = (long)blockIdx.x * C_CHUNK;
    const int  cn = (int)min((long)C_CHUNK, (long)N_EDGES - e0);

    for (int i = tid; i < NB; i += 512) { l_cnt[i] = 0; l_cnt2[i] = 0; }
    __syncthreads();

    // load edges into registers, count both key spaces
    unsigned r_pk[8];
    short    r_bk[8];
    #pragma unroll
    for (int k = 0; k < 8; ++k) {
        int i = tid + k * 512;
        r_bk[k] = -1;
        if (i < cn) {
            int d = dst[e0 + i];
            int s = src[e0 + i];
            int bk = d >> 8;
            r_bk[k] = (short)bk;
            r_pk[k] = ((unsigned)(d & 255) << 17) | (unsigned)s;
            atomicAdd(&l_cnt[bk], 1);
            atomicAdd(&l_cnt2[s >> 8], 1);
        }
    }
    __syncthreads();

    {   // scan 1: dst buckets -> l_base/l_pos, reserve global runs
        int v = (tid < NB) ? l_cnt[tid] : 0;
        int inc = v;
        #pragma unroll
        for (int off = 1; off < 64; off <<= 1) {
            int t = __shfl_up(inc, off);
            if (lane >= off) inc += t;
        }
        if (lane == 63) wsum_s[wid] = inc;
        __syncthreads();
        int woff = 0;
        #pragma unroll
        for (int w = 0; w < 8; ++w) if (w < wid) woff += wsum_s[w];
        int excl = woff + inc - v;
        if (tid < NB) {
            l_base[tid] = excl;
            l_pos[tid]  = excl;
            g_base[tid] = v ? atomicAdd(&bucket_cnt[tid], v) : 0;
        }
    }
    __syncthreads();
    {   // scan 2: src buckets (wsum_s reused after barrier)
        int v = (tid < NB) ? l_cnt2[tid] : 0;
        int inc = v;
        #pragma unroll
        for (int off = 1; off < 64; off <<= 1) {
            int t = __shfl_up(inc, off);
            if (lane >= off) inc += t;
        }
        if (lane == 63) wsum_s[wid] = inc;
        __syncthreads();
        int woff = 0;
        #pragma unroll
        for (int w = 0; w < 8; ++w) if (w < wid) woff += wsum_s[w];
        int excl = woff + inc - v;
        if (tid < NB) {
            l_base2[tid] = excl;
            l_pos2[tid]  = excl;
            g_base2[tid] = v ? atomicAdd(&bucket_cnt2[tid], v) : 0;
        }
    }
    __syncthreads();

    // scatter into LDS: both counting sorts
    #pragma unroll
    for (int k = 0; k < 8; ++k) {
        if (r_bk[k] >= 0) {
            unsigned pk = r_pk[k];
            int p = atomicAdd(&l_pos[(int)r_bk[k]], 1);
            buf[p] = pk;
            bkt_of[p] = (unsigned short)r_bk[k];
            int bk2 = (int)((pk >> 8) & 0x1FF);        // src >> 8
            int p2 = atomicAdd(&l_pos2[bk2], 1);
            bbuf[p2] = (unsigned char)(pk & 255);      // src & 255
            bkt2_of[p2] = (unsigned short)bk2;
        }
    }
    __syncthreads();

    // coalesced flushes: consecutive i -> consecutive global slot within run
    for (int i = tid; i < cn; i += 512) {
        int bk = bkt_of[i];
        int gp = g_base[bk] + (i - l_base[bk]);
        if (gp < CAPB)                                 // 22-sigma safety
            pairs[(long)bk * CAPB + gp] = buf[i];
        int b2 = bkt2_of[i];
        int gp2 = g_base2[b2] + (i - l_base2[b2]);
        if (gp2 < CAPB)
            sbytes[(long)b2 * CAPB + gp2] = bbuf[i];
    }
}

// ---- Kernel 2: per-src-bucket LDS histogram -> deg_out (no global atomics) ----
__global__ __launch_bounds__(256) void count_kernel(
        const unsigned char* __restrict__ sbytes, const int* __restrict__ bucket_cnt2,
        int* __restrict__ deg_out_i) {
    __shared__ int hist[BUCKET_NODES];
    const int tid = threadIdx.x;
    const int bk  = blockIdx.x;
    hist[tid] = 0;
    __syncthreads();

    const int cnt = min(bucket_cnt2[bk], CAPB);
    const unsigned* sb4 = (const unsigned*)(sbytes + (long)bk * CAPB);
    const int n4 = cnt >> 2;
    for (int i = tid; i < n4; i += 256) {
        unsigned u = sb4[i];
        atomicAdd(&hist[u & 255], 1);
        atomicAdd(&hist[(u >> 8) & 255], 1);
        atomicAdd(&hist[(u >> 16) & 255], 1);
        atomicAdd(&hist[u >> 24], 1);
    }
    for (int i = (n4 << 2) + tid; i < cnt; i += 256)
        atomicAdd(&hist[sbytes[(long)bk * CAPB + i]], 1);
    __syncthreads();

    const int node = bk * BUCKET_NODES + tid;
    if (node < N_NODES) deg_out_i[node] = hist[tid];
}

// ---- Kernel 3: sxw[n,:] = bf16( (X[n,:] @ W) * rsqrt(max(deg_out[n],1)) ) ----
__global__ __launch_bounds__(256) void gemm_scale_kernel(
        const float* __restrict__ x, const float* __restrict__ W,
        const int* __restrict__ deg_out_i, __hip_bfloat16* __restrict__ sxw) {
    __shared__ float Wl[IN_F * OUT_F];    // 32 KB
    __shared__ float xl[R_TILE * IN_F];   // 8 KB
    const int tid = threadIdx.x;
    for (int i = tid; i < IN_F * OUT_F; i += 256) Wl[i] = W[i];

    const int sub = tid >> 6;             // wave 0..3 -> rows sub*4 .. sub*4+3
    const int col = tid & 63;
    const int n_groups = N_NODES / R_TILE;   // 6250, exact

    for (int g = blockIdx.x; g < n_groups; g += gridDim.x) {
        __syncthreads();
        const float4* xg = (const float4*)(x + (long)g * R_TILE * IN_F);
        float4* xl4 = (float4*)xl;
        xl4[tid]       = xg[tid];
        xl4[tid + 256] = xg[tid + 256];
        __syncthreads();

        float a0 = 0.0f, a1 = 0.0f, a2 = 0.0f, a3 = 0.0f;
        const float* xr = &xl[sub * 4 * IN_F];
        #pragma unroll
        for (int k4 = 0; k4 < IN_F / 4; ++k4) {
            float4 x0 = ((const float4*)xr)[k4];
            float4 x1 = ((const float4*)(xr + IN_F))[k4];
            float4 x2 = ((const float4*)(xr + 2 * IN_F))[k4];
            float4 x3 = ((const float4*)(xr + 3 * IN_F))[k4];
            float w0 = Wl[(k4 * 4 + 0) * OUT_F + col];
            float w1 = Wl[(k4 * 4 + 1) * OUT_F + col];
            float w2 = Wl[(k4 * 4 + 2) * OUT_F + col];
            float w3 = Wl[(k4 * 4 + 3) * OUT_F + col];
            a0 += x0.x * w0 + x0.y * w1 + x0.z * w2 + x0.w * w3;
            a1 += x1.x * w0 + x1.y * w1 + x1.z * w2 + x1.w * w3;
            a2 += x2.x * w0 + x2.y * w1 + x2.z * w2 + x2.w * w3;
            a3 += x3.x * w0 + x3.y * w1 + x3.z * w2 + x3.w * w3;
        }

        const int r0 = g * R_TILE + sub * 4;
        int d0 = deg_out_i[r0 + 0], d1 = deg_out_i[r0 + 1];
        int d2 = deg_out_i[r0 + 2], d3 = deg_out_i[r0 + 3];
        float s0 = rsqrtf((float)(d0 < 1 ? 1 : d0));
        float s1 = rsqrtf((float)(d1 < 1 ? 1 : d1));
        float s2 = rsqrtf((float)(d2 < 1 ? 1 : d2));
        float s3 = rsqrtf((float)(d3 < 1 ? 1 : d3));
        sxw[(long)(r0 + 0) * OUT_F + col] = __float2bfloat16(a0 * s0);
        sxw[(long)(r0 + 1) * OUT_F + col] = __float2bfloat16(a1 * s1);
        sxw[(long)(r0 + 2) * OUT_F + col] = __float2bfloat16(a2 * s2);
        sxw[(long)(r0 + 3) * OUT_F + col] = __float2bfloat16(a3 * s3);
    }
}

// ---- Kernel 4: per-bucket LDS counting sort -> row_beg/row_deg + sorted src ----
__global__ __launch_bounds__(512) void csr_kernel(
        unsigned* __restrict__ pairs, const int* __restrict__ bucket_cnt,
        int* __restrict__ row_beg, int* __restrict__ row_deg) {
    __shared__ int hist[BUCKET_NODES];
    __shared__ int cur[BUCKET_NODES];
    __shared__ int wsum[4];
    __shared__ unsigned buf[CAPB];       // 40 KB
    const int tid  = threadIdx.x;
    const int lane = tid & 63;
    const int wid  = tid >> 6;
    const int bk   = blockIdx.x;
    const long base = (long)bk * CAPB;
    const int cnt  = min(bucket_cnt[bk], CAPB);

    if (tid < 256) hist[tid] = 0;
    __syncthreads();

    for (int i = tid; i < cnt; i += 512) {
        unsigned e = pairs[base + i];
        buf[i] = e;
        atomicAdd(&hist[e >> 17], 1);
    }
    __syncthreads();

    int v = (tid < 256) ? hist[tid] : 0;
    int inc = v;
    #pragma unroll
    for (int off = 1; off < 64; off <<= 1) {
        int t = __shfl_up(inc, off);
        if (lane >= off) inc += t;
    }
    if (tid < 256 && lane == 63) wsum[wid] = inc;
    __syncthreads();
    if (tid < 256) {
        int woff = 0;
        #pragma unroll
        for (int w = 0; w < 4; ++w) if (w < wid) woff += wsum[w];
        int excl = woff + inc - v;
        cur[tid] = excl;
        const int node = bk * BUCKET_NODES + tid;
        if (node < N_NODES) {
            row_beg[node] = (int)(base + excl);
            row_deg[node] = v;
        }
    }
    __syncthreads();

    for (int i = tid; i < cnt; i += 512) {
        unsigned e = buf[i];
        int p = atomicAdd(&cur[e >> 17], 1);
        pairs[base + p] = e & 0x1FFFF;   // plain src, node-sorted
    }
}

// ---- Kernel 5: gather-sum per dst node, uint4 (16B) loads ----
#define ACC8(u)                                   \
    a0 += __uint_as_float((u).x << 16);           \
    a1 += __uint_as_float((u).x & 0xFFFF0000u);   \
    a2 += __uint_as_float((u).y << 16);           \
    a3 += __uint_as_float((u).y & 0xFFFF0000u);   \
    a4 += __uint_as_float((u).z << 16);           \
    a5 += __uint_as_float((u).z & 0xFFFF0000u);   \
    a6 += __uint_as_float((u).w << 16);           \
    a7 += __uint_as_float((u).w & 0xFFFF0000u);

__global__ __launch_bounds__(256) void gather_kernel(
        const int* __restrict__ row_beg, const int* __restrict__ row_deg,
        const unsigned* __restrict__ csr_src, const uint4* __restrict__ sxw4,
        const float* __restrict__ b, float* __restrict__ out) {
    const int lane = threadIdx.x & 63;
    const int node = blockIdx.x * 4 + (threadIdx.x >> 6);
    if (node >= N_NODES) return;

    const int eo = lane >> 3;     // edge slot 0..7
    const int c  = lane & 7;      // uint4 index within row (8 cols)

    const int beg = row_beg[node];
    const int deg = row_deg[node];
    const int end = beg + deg;

    float a0 = 0, a1 = 0, a2 = 0, a3 = 0, a4 = 0, a5 = 0, a6 = 0, a7 = 0;

    int j = beg;
    for (; j + 16 <= end; j += 16) {
        unsigned sA = csr_src[j + eo];
        unsigned sB = csr_src[j + 8 + eo];
        uint4 uA = sxw4[(long)sA * 8 + c];
        uint4 uB = sxw4[(long)sB * 8 + c];
        ACC8(uA)
        ACC8(uB)
    }
    for (; j + 8 <= end; j += 8) {
        unsigned s = csr_src[j + eo];
        uint4 u = sxw4[(long)s * 8 + c];
        ACC8(u)
    }
    if (j < end) {
        int e = j + eo;
        if (e < end) {
            unsigned s = csr_src[e];
            uint4 u = sxw4[(long)s * 8 + c];
            ACC8(u)
        }
    }

    #pragma unroll
    for (int off = 8; off < 64; off <<= 1) {
        a0 += __shfl_xor(a0, off);
        a1 += __shfl_xor(a1, off);
        a2 += __shfl_xor(a2, off);
        a3 += __shfl_xor(a3, off);
        a4 += __shfl_xor(a4, off);
        a5 += __shfl_xor(a5, off);
        a6 += __shfl_xor(a6, off);
        a7 += __shfl_xor(a7, off);
    }

    if (lane < 8) {
        float d = (float)(deg < 1 ? 1 : deg);
        float s = rsqrtf(d);
        float4 b0 = ((const float4*)b)[c * 2];
        float4 b1 = ((const float4*)b)[c * 2 + 1];
        float4 o0, o1;
        o0.x = a0 * s + b0.x; o0.x = o0.x > 0.0f ? o0.x : 0.0f;
        o0.y = a1 * s + b0.y; o0.y = o0.y > 0.0f ? o0.y : 0.0f;
        o0.z = a2 * s + b0.z; o0.z = o0.z > 0.0f ? o0.z : 0.0f;
        o0.w = a3 * s + b0.w; o0.w = o0.w > 0.0f ? o0.w : 0.0f;
        o1.x = a4 * s + b1.x; o1.x = o1.x > 0.0f ? o1.x : 0.0f;
        o1.y = a5 * s + b1.y; o1.y = o1.y > 0.0f ? o1.y : 0.0f;
        o1.z = a6 * s + b1.z; o1.z = o1.z > 0.0f ? o1.z : 0.0f;
        o1.w = a7 * s + b1.w; o1.w = o1.w > 0.0f ? o1.w : 0.0f;
        float4* orow = (float4*)(out + (long)node * OUT_F);
        orow[c * 2]     = o0;
        orow[c * 2 + 1] = o1;
    }
}

extern "C" void kernel_launch(void* const* d_in, const int* in_sizes, int n_in,
                              void* d_out, int out_size, void* d_ws, size_t ws_size,
                              hipStream_t stream) {
    const float* in_feat = (const float*)d_in[0];
    const int*   src     = (const int*)d_in[1];
    const int*   dst     = (const int*)d_in[2];
    const float* W       = (const float*)d_in[3];
    const float* b       = (const float*)d_in[4];
    float*       out     = (float*)d_out;

    // ws: sxw bf16 [N*64] (12.8MB) | deg_out [N] | bucket_cnt [NB] | bucket_cnt2 [NB]
    //   | row_beg [N] | row_deg [N] | pairs [NB*CAPB u32] (16MB) | sbytes [NB*CAPB] (4MB)
    __hip_bfloat16* sxw         = (__hip_bfloat16*)d_ws;
    int*            deg_out_i   = (int*)(sxw + (size_t)N_NODES * OUT_F);
    int*            bucket_cnt  = deg_out_i + N_NODES;
    int*            bucket_cnt2 = bucket_cnt + NB;
    int*            row_beg     = bucket_cnt2 + NB;
    int*            row_deg     = row_beg + N_NODES;
    unsigned*       pairs       = (unsigned*)(row_deg + N_NODES);
    unsigned char*  sbytes      = (unsigned char*)(pairs + (size_t)NB * CAPB);

    // zero only the two bucket counters (deg_out is fully overwritten by count)
    hipMemsetAsync(bucket_cnt, 0, 2 * (size_t)NB * sizeof(int), stream);

    partition_kernel<<<C_BLOCKS, 512, 0, stream>>>(src, dst, bucket_cnt,
                                                   bucket_cnt2, pairs, sbytes);

    count_kernel<<<NB, 256, 0, stream>>>(sbytes, bucket_cnt2, deg_out_i);

    gemm_scale_kernel<<<2048, 256, 0, stream>>>(in_feat, W, deg_out_i, sxw);

    csr_kernel<<<NB, 512, 0, stream>>>(pairs, bucket_cnt, row_beg, row_deg);

    gather_kernel<<<(N_NODES + 3) / 4, 256, 0, stream>>>(row_beg, row_deg, pairs,
                                                         (const uint4*)sxw, b, out);
}

// Round 11
// 259.261 us; speedup vs baseline: 1.4863x; 1.0385x over previous
//
#include <hip/hip_runtime.h>
#include <hip/hip_bf16.h>

// GCN GraphConv (norm='both', mult-first): out = relu( D_in^-1/2 * A * D_out^-1/2 * (X W) + b )
// N=100000 nodes, E=3200000 edges, IN=128, OUT=64, fp32 in/out.
//
// Strategy R11 (on R10's no-global-atomic pipeline):
//  - partition: int4-vectorized edge loads (VMEM instrs /4).
//  - mega_kernel: csr counting sort (blocks < NB) FUSED with 512-thread gemm
//    (blocks >= NB) — independent stages, opposite pipes, co-resident.
//  - gather: 4 row-loads in flight (j+32 main loop).

constexpr int N_NODES = 100000;
constexpr int N_EDGES = 3200000;
constexpr int IN_F    = 128;
constexpr int OUT_F   = 64;
constexpr int BUCKET_NODES = 256;
constexpr int NB   = (N_NODES + BUCKET_NODES - 1) / BUCKET_NODES;  // 391
constexpr int CAPB = 10240;          // bucket capacity; mean 8184, sd~90 -> 22 sigma
constexpr int C_CHUNK  = 4096;
constexpr int C_BLOCKS = (N_EDGES + C_CHUNK - 1) / C_CHUNK;        // 782 (last cn=1024, %4==0)
constexpr int G_TILE   = 32;         // gemm rows per block-iteration (512 thr)
constexpr int G_BLOCKS = 1024;
constexpr int G_GROUPS = N_NODES / G_TILE;                         // 3125

// ---- Kernel 1: dual partition (dst pairs + src bytes), vectorized loads ----
__global__ __launch_bounds__(512) void partition_kernel(
        const int* __restrict__ src, const int* __restrict__ dst,
        int* __restrict__ bucket_cnt, int* __restrict__ bucket_cnt2,
        unsigned* __restrict__ pairs, unsigned char* __restrict__ sbytes) {
    __shared__ int l_cnt [NB], l_base [NB], l_pos [NB], g_base [NB];
    __shared__ int l_cnt2[NB], l_base2[NB], l_pos2[NB], g_base2[NB];
    __shared__ int wsum_s[8];
    __shared__ unsigned buf[C_CHUNK];             // 16 KB (dst-sorted pairs)
    __shared__ unsigned short bkt_of[C_CHUNK];    // 8 KB
    __shared__ unsigned char  bbuf[C_CHUNK];      // 4 KB (src-sorted local ids)
    __shared__ unsigned short bkt2_of[C_CHUNK];   // 8 KB
    const int tid  = threadIdx.x;
    const int lane = tid & 63;
    const int wid  = tid >> 6;                    // 0..7
    const long e0 = (long)blockIdx.x * C_CHUNK;
    const int  cn = (int)min((long)C_CHUNK, (long)N_EDGES - e0);
    const int  cn4 = cn >> 2;                     // cn is always a multiple of 4

    for (int i = tid; i < NB; i += 512) { l_cnt[i] = 0; l_cnt2[i] = 0; }
    __syncthreads();

    // load edges as int4 (4 edges per load), count both key spaces
    unsigned r_pk[8];
    short    r_bk[8];
    const int4* d4p = (const int4*)(dst + e0);
    const int4* s4p = (const int4*)(src + e0);
    #pragma unroll
    for (int k = 0; k < 2; ++k) {
        int i4 = tid + k * 512;
        int rb = k * 4;
        if (i4 < cn4) {
            int4 d4 = d4p[i4];
            int4 s4 = s4p[i4];
            int dd[4] = {d4.x, d4.y, d4.z, d4.w};
            int ss[4] = {s4.x, s4.y, s4.z, s4.w};
            #pragma unroll
            for (int j = 0; j < 4; ++j) {
                int bk = dd[j] >> 8;
                r_bk[rb + j] = (short)bk;
                r_pk[rb + j] = ((unsigned)(dd[j] & 255) << 17) | (unsigned)ss[j];
                atomicAdd(&l_cnt[bk], 1);
                atomicAdd(&l_cnt2[ss[j] >> 8], 1);
            }
        } else {
            #pragma unroll
            for (int j = 0; j < 4; ++j) r_bk[rb + j] = -1;
        }
    }
    __syncthreads();

    {   // scan 1: dst buckets -> l_base/l_pos, reserve global runs
        int v = (tid < NB) ? l_cnt[tid] : 0;
        int inc = v;
        #pragma unroll
        for (int off = 1; off < 64; off <<= 1) {
            int t = __shfl_up(inc, off);
            if (lane >= off) inc += t;
        }
        if (lane == 63) wsum_s[wid] = inc;
        __syncthreads();
        int woff = 0;
        #pragma unroll
        for (int w = 0; w < 8; ++w) if (w < wid) woff += wsum_s[w];
        int excl = woff + inc - v;
        if (tid < NB) {
            l_base[tid] = excl;
            l_pos[tid]  = excl;
            g_base[tid] = v ? atomicAdd(&bucket_cnt[tid], v) : 0;
        }
    }
    __syncthreads();
    {   // scan 2: src buckets
        int v = (tid < NB) ? l_cnt2[tid] : 0;
        int inc = v;
        #pragma unroll
        for (int off = 1; off < 64; off <<= 1) {
            int t = __shfl_up(inc, off);
            if (lane >= off) inc += t;
        }
        if (lane == 63) wsum_s[wid] = inc;
        __syncthreads();
        int woff = 0;
        #pragma unroll
        for (int w = 0; w < 8; ++w) if (w < wid) woff += wsum_s[w];
        int excl = woff + inc - v;
        if (tid < NB) {
            l_base2[tid] = excl;
            l_pos2[tid]  = excl;
            g_base2[tid] = v ? atomicAdd(&bucket_cnt2[tid], v) : 0;
        }
    }
    __syncthreads();

    // scatter into LDS: both counting sorts
    #pragma unroll
    for (int k = 0; k < 8; ++k) {
        if (r_bk[k] >= 0) {
            unsigned pk = r_pk[k];
            int p = atomicAdd(&l_pos[(int)r_bk[k]], 1);
            buf[p] = pk;
            bkt_of[p] = (unsigned short)r_bk[k];
            int bk2 = (int)((pk >> 8) & 0x1FF);        // src >> 8
            int p2 = atomicAdd(&l_pos2[bk2], 1);
            bbuf[p2] = (unsigned char)(pk & 255);      // src & 255
            bkt2_of[p2] = (unsigned short)bk2;
        }
    }
    __syncthreads();

    // coalesced flushes
    for (int i = tid; i < cn; i += 512) {
        int bk = bkt_of[i];
        int gp = g_base[bk] + (i - l_base[bk]);
        if (gp < CAPB)                                 // 22-sigma safety
            pairs[(long)bk * CAPB + gp] = buf[i];
        int b2 = bkt2_of[i];
        int gp2 = g_base2[b2] + (i - l_base2[b2]);
        if (gp2 < CAPB)
            sbytes[(long)b2 * CAPB + gp2] = bbuf[i];
    }
}

// ---- Kernel 2: per-src-bucket LDS histogram -> deg_out ----
__global__ __launch_bounds__(256) void count_kernel(
        const unsigned char* __restrict__ sbytes, const int* __restrict__ bucket_cnt2,
        int* __restrict__ deg_out_i) {
    __shared__ int hist[BUCKET_NODES];
    const int tid = threadIdx.x;
    const int bk  = blockIdx.x;
    hist[tid] = 0;
    __syncthreads();

    const int cnt = min(bucket_cnt2[bk], CAPB);
    const unsigned* sb4 = (const unsigned*)(sbytes + (long)bk * CAPB);
    const int n4 = cnt >> 2;
    for (int i = tid; i < n4; i += 256) {
        unsigned u = sb4[i];
        atomicAdd(&hist[u & 255], 1);
        atomicAdd(&hist[(u >> 8) & 255], 1);
        atomicAdd(&hist[(u >> 16) & 255], 1);
        atomicAdd(&hist[u >> 24], 1);
    }
    for (int i = (n4 << 2) + tid; i < cnt; i += 256)
        atomicAdd(&hist[sbytes[(long)bk * CAPB + i]], 1);
    __syncthreads();

    const int node = bk * BUCKET_NODES + tid;
    if (node < N_NODES) deg_out_i[node] = hist[tid];
}

// ---- Kernel 3 (mega): blocks < NB: csr counting sort; blocks >= NB: gemm ----
__global__ __launch_bounds__(512) void mega_kernel(
        unsigned* __restrict__ pairs, const int* __restrict__ bucket_cnt,
        int* __restrict__ row_beg, int* __restrict__ row_deg,
        const float* __restrict__ x, const float* __restrict__ W,
        const int* __restrict__ deg_out_i, __hip_bfloat16* __restrict__ sxw) {
    alignas(16) __shared__ char smem[49152];       // union: csr 43KB | gemm 48KB
    const int tid = threadIdx.x;

    if (blockIdx.x < NB) {
        // ---------------- csr path ----------------
        unsigned* buf  = (unsigned*)smem;                    // 40960 B
        int*      hist = (int*)(smem + 40960);               // 1024 B
        int*      cur  = (int*)(smem + 40960 + 1024);        // 1024 B
        int*      wsum = (int*)(smem + 40960 + 2048);        // 16 B
        const int lane = tid & 63;
        const int wid  = tid >> 6;
        const int bk   = blockIdx.x;
        const long base = (long)bk * CAPB;
        const int cnt  = min(bucket_cnt[bk], CAPB);

        if (tid < 256) hist[tid] = 0;
        __syncthreads();

        const int c4 = cnt >> 2;
        const uint4* p4 = (const uint4*)(pairs + base);
        for (int i4 = tid; i4 < c4; i4 += 512) {
            uint4 e4 = p4[i4];
            ((uint4*)buf)[i4] = e4;                           // ds_write_b128
            atomicAdd(&hist[e4.x >> 17], 1);
            atomicAdd(&hist[e4.y >> 17], 1);
            atomicAdd(&hist[e4.z >> 17], 1);
            atomicAdd(&hist[e4.w >> 17], 1);
        }
        for (int i = (c4 << 2) + tid; i < cnt; i += 512) {
            unsigned e = pairs[base + i];
            buf[i] = e;
            atomicAdd(&hist[e >> 17], 1);
        }
        __syncthreads();

        int v = (tid < 256) ? hist[tid] : 0;
        int inc = v;
        #pragma unroll
        for (int off = 1; off < 64; off <<= 1) {
            int t = __shfl_up(inc, off);
            if (lane >= off) inc += t;
        }
        if (tid < 256 && lane == 63) wsum[wid] = inc;
        __syncthreads();
        if (tid < 256) {
            int woff = 0;
            #pragma unroll
            for (int w = 0; w < 4; ++w) if (w < wid) woff += wsum[w];
            int excl = woff + inc - v;
            cur[tid] = excl;
            const int node = bk * BUCKET_NODES + tid;
            if (node < N_NODES) {
                row_beg[node] = (int)(base + excl);
                row_deg[node] = v;
            }
        }
        __syncthreads();

        for (int i = tid; i < cnt; i += 512) {
            unsigned e = buf[i];
            int p = atomicAdd(&cur[e >> 17], 1);
            pairs[base + p] = e & 0x1FFFF;   // plain src, node-sorted
        }
    } else {
        // ---------------- gemm path ----------------
        float* Wl = (float*)smem;                  // 32768 B
        float* xl = (float*)(smem + 32768);        // 16384 B (32 rows x 128)
        for (int i = tid; i < IN_F * OUT_F; i += 512) Wl[i] = W[i];

        const int sub = tid >> 6;                  // 0..7 -> rows sub*4..sub*4+3
        const int col = tid & 63;
        const int bid = blockIdx.x - NB;

        for (int g = bid; g < G_GROUPS; g += G_BLOCKS) {
            __syncthreads();
            const float4* xg = (const float4*)(x + (long)g * G_TILE * IN_F);
            float4* xl4 = (float4*)xl;
            xl4[tid]       = xg[tid];
            xl4[tid + 512] = xg[tid + 512];
            __syncthreads();

            float a0 = 0.0f, a1 = 0.0f, a2 = 0.0f, a3 = 0.0f;
            const float* xr = xl + sub * 4 * IN_F;
            #pragma unroll
            for (int k4 = 0; k4 < IN_F / 4; ++k4) {
                float4 x0 = ((const float4*)xr)[k4];
                float4 x1 = ((const float4*)(xr + IN_F))[k4];
                float4 x2 = ((const float4*)(xr + 2 * IN_F))[k4];
                float4 x3 = ((const float4*)(xr + 3 * IN_F))[k4];
                float w0 = Wl[(k4 * 4 + 0) * OUT_F + col];
                float w1 = Wl[(k4 * 4 + 1) * OUT_F + col];
                float w2 = Wl[(k4 * 4 + 2) * OUT_F + col];
                float w3 = Wl[(k4 * 4 + 3) * OUT_F + col];
                a0 += x0.x * w0 + x0.y * w1 + x0.z * w2 + x0.w * w3;
                a1 += x1.x * w0 + x1.y * w1 + x1.z * w2 + x1.w * w3;
                a2 += x2.x * w0 + x2.y * w1 + x2.z * w2 + x2.w * w3;
                a3 += x3.x * w0 + x3.y * w1 + x3.z * w2 + x3.w * w3;
            }

            const int r0 = g * G_TILE + sub * 4;
            int d0 = deg_out_i[r0 + 0], d1 = deg_out_i[r0 + 1];
            int d2 = deg_out_i[r0 + 2], d3 = deg_out_i[r0 + 3];
            float s0 = rsqrtf((float)(d0 < 1 ? 1 : d0));
            float s1 = rsqrtf((float)(d1 < 1 ? 1 : d1));
            float s2 = rsqrtf((float)(d2 < 1 ? 1 : d2));
            float s3 = rsqrtf((float)(d3 < 1 ? 1 : d3));
            sxw[(long)(r0 + 0) * OUT_F + col] = __float2bfloat16(a0 * s0);
            sxw[(long)(r0 + 1) * OUT_F + col] = __float2bfloat16(a1 * s1);
            sxw[(long)(r0 + 2) * OUT_F + col] = __float2bfloat16(a2 * s2);
            sxw[(long)(r0 + 3) * OUT_F + col] = __float2bfloat16(a3 * s3);
        }
    }
}

// ---- Kernel 4: gather-sum per dst node, uint4 loads, 4 in flight ----
#define ACC8(u)                                   \
    a0 += __uint_as_float((u).x << 16);           \
    a1 += __uint_as_float((u).x & 0xFFFF0000u);   \
    a2 += __uint_as_float((u).y << 16);           \
    a3 += __uint_as_float((u).y & 0xFFFF0000u);   \
    a4 += __uint_as_float((u).z << 16);           \
    a5 += __uint_as_float((u).z & 0xFFFF0000u);   \
    a6 += __uint_as_float((u).w << 16);           \
    a7 += __uint_as_float((u).w & 0xFFFF0000u);

__global__ __launch_bounds__(256) void gather_kernel(
        const int* __restrict__ row_beg, const int* __restrict__ row_deg,
        const unsigned* __restrict__ csr_src, const uint4* __restrict__ sxw4,
        const float* __restrict__ b, float* __restrict__ out) {
    const int lane = threadIdx.x & 63;
    const int node = blockIdx.x * 4 + (threadIdx.x >> 6);

    const int eo = lane >> 3;     // edge slot 0..7
    const int c  = lane & 7;      // uint4 index within row (8 cols)

    const int beg = row_beg[node];
    const int deg = row_deg[node];
    const int end = beg + deg;

    float a0 = 0, a1 = 0, a2 = 0, a3 = 0, a4 = 0, a5 = 0, a6 = 0, a7 = 0;

    int j = beg;
    for (; j + 32 <= end; j += 32) {            // 4 row-loads in flight
        unsigned s0 = csr_src[j + eo];
        unsigned s1 = csr_src[j + 8 + eo];
        unsigned s2 = csr_src[j + 16 + eo];
        unsigned s3 = csr_src[j + 24 + eo];
        uint4 u0 = sxw4[(long)s0 * 8 + c];
        uint4 u1 = sxw4[(long)s1 * 8 + c];
        uint4 u2 = sxw4[(long)s2 * 8 + c];
        uint4 u3 = sxw4[(long)s3 * 8 + c];
        ACC8(u0) ACC8(u1) ACC8(u2) ACC8(u3)
    }
    for (; j + 8 <= end; j += 8) {
        unsigned s = csr_src[j + eo];
        uint4 u = sxw4[(long)s * 8 + c];
        ACC8(u)
    }
    if (j < end) {
        int e = j + eo;
        if (e < end) {
            unsigned s = csr_src[e];
            uint4 u = sxw4[(long)s * 8 + c];
            ACC8(u)
        }
    }

    #pragma unroll
    for (int off = 8; off < 64; off <<= 1) {
        a0 += __shfl_xor(a0, off);
        a1 += __shfl_xor(a1, off);
        a2 += __shfl_xor(a2, off);
        a3 += __shfl_xor(a3, off);
        a4 += __shfl_xor(a4, off);
        a5 += __shfl_xor(a5, off);
        a6 += __shfl_xor(a6, off);
        a7 += __shfl_xor(a7, off);
    }

    if (lane < 8) {
        float d = (float)(deg < 1 ? 1 : deg);
        float s = rsqrtf(d);
        float4 b0 = ((const float4*)b)[c * 2];
        float4 b1 = ((const float4*)b)[c * 2 + 1];
        float4 o0, o1;
        o0.x = a0 * s + b0.x; o0.x = o0.x > 0.0f ? o0.x : 0.0f;
        o0.y = a1 * s + b0.y; o0.y = o0.y > 0.0f ? o0.y : 0.0f;
        o0.z = a2 * s + b0.z; o0.z = o0.z > 0.0f ? o0.z : 0.0f;
        o0.w = a3 * s + b0.w; o0.w = o0.w > 0.0f ? o0.w : 0.0f;
        o1.x = a4 * s + b1.x; o1.x = o1.x > 0.0f ? o1.x : 0.0f;
        o1.y = a5 * s + b1.y; o1.y = o1.y > 0.0f ? o1.y : 0.0f;
        o1.z = a6 * s + b1.z; o1.z = o1.z > 0.0f ? o1.z : 0.0f;
        o1.w = a7 * s + b1.w; o1.w = o1.w > 0.0f ? o1.w : 0.0f;
        float4* orow = (float4*)(out + (long)node * OUT_F);
        orow[c * 2]     = o0;
        orow[c * 2 + 1] = o1;
    }
}

extern "C" void kernel_launch(void* const* d_in, const int* in_sizes, int n_in,
                              void* d_out, int out_size, void* d_ws, size_t ws_size,
                              hipStream_t stream) {
    const float* in_feat = (const float*)d_in[0];
    const int*   src     = (const int*)d_in[1];
    const int*   dst     = (const int*)d_in[2];
    const float* W       = (const float*)d_in[3];
    const float* b       = (const float*)d_in[4];
    float*       out     = (float*)d_out;

    // ws: sxw bf16 [N*64] (12.8MB) | deg_out [N] | bucket_cnt [NB] | bucket_cnt2 [NB]
    //   | row_beg [N] | row_deg [N] | pairs [NB*CAPB u32] (16MB) | sbytes [NB*CAPB] (4MB)
    __hip_bfloat16* sxw         = (__hip_bfloat16*)d_ws;
    int*            deg_out_i   = (int*)(sxw + (size_t)N_NODES * OUT_F);
    int*            bucket_cnt  = deg_out_i + N_NODES;
    int*            bucket_cnt2 = bucket_cnt + NB;
    int*            row_beg     = bucket_cnt2 + NB;
    int*            row_deg     = row_beg + N_NODES;
    unsigned*       pairs       = (unsigned*)(row_deg + N_NODES);
    unsigned char*  sbytes      = (unsigned char*)(pairs + (size_t)NB * CAPB);

    hipMemsetAsync(bucket_cnt, 0, 2 * (size_t)NB * sizeof(int), stream);

    partition_kernel<<<C_BLOCKS, 512, 0, stream>>>(src, dst, bucket_cnt,
                                                   bucket_cnt2, pairs, sbytes);

    count_kernel<<<NB, 256, 0, stream>>>(sbytes, bucket_cnt2, deg_out_i);

    mega_kernel<<<NB + G_BLOCKS, 512, 0, stream>>>(pairs, bucket_cnt,
                                                   row_beg, row_deg,
                                                   in_feat, W, deg_out_i, sxw);

    gather_kernel<<<N_NODES / 4, 256, 0, stream>>>(row_beg, row_deg, pairs,
                                                   (const uint4*)sxw, b, out);
}